// Round 3
// baseline (434.729 us; speedup 1.0000x reference)
//
#include <hip/hip_runtime.h>
#include <stdint.h>

// Problem constants
#define ZSIZE   8388608      // 32*256*32*32
#define NPIX    32768        // 32*32*32
#define IDX_OFF ZSIZE        // idx output offset (floats) in d_out
#define LOSS_OFF (ZSIZE + NPIX)
#define ET_OFF  1024         // Et fp32 [256][1024] scratch (for kse)
#define E1_OFF  263168       // e1 bf16 [1024][256] (131072 floats)
#define ZT_OFF  394240       // zt bf16 [32][1024][256] (4194304 floats)
#define CAP     24           // candidate slots per pixel
#define WWIN    6.0e-3f      // window >= 2*eps_bound (eps<=1.7e-3, margin 1.8x)

using v8s = __attribute__((ext_vector_type(8))) short;   // 8 bf16 (4 VGPR)
using v4f = __attribute__((ext_vector_type(4))) float;   // MFMA acc

__device__ __forceinline__ unsigned short bf16rne(float f) {
  unsigned u = __float_as_uint(f);
  return (unsigned short)((u + 0x7FFFu + ((u >> 16) & 1u)) >> 16);
}

// ---------------------------------------------------------------------------
// ktr: transpose embedding E[1024][256] -> Et[256][1024] (feeds kse only)
// ---------------------------------------------------------------------------
__global__ __launch_bounds__(256) void ktr(const float* __restrict__ E,
                                           float* __restrict__ out) {
  __shared__ float tile[64][65];
  const int k0 = blockIdx.x * 64;
  const int c0 = blockIdx.y * 64;
  const int t = threadIdx.x;
  #pragma unroll
  for (int i = 0; i < 4; i++) {
    int f = t + 256 * i;
    int r = f >> 4, q = f & 15;
    float4 e = *(const float4*)(E + (k0 + r) * 256 + c0 + 4 * q);
    tile[r][4 * q + 0] = e.x; tile[r][4 * q + 1] = e.y;
    tile[r][4 * q + 2] = e.z; tile[r][4 * q + 3] = e.w;
  }
  __syncthreads();
  #pragma unroll
  for (int i = 0; i < 4; i++) {
    int f = t + 256 * i;
    int cr = f >> 4, kq = f & 15;
    float4 o;
    o.x = tile[4 * kq + 0][cr];
    o.y = tile[4 * kq + 1][cr];
    o.z = tile[4 * kq + 2][cr];
    o.w = tile[4 * kq + 3][cr];
    *(float4*)(out + ET_OFF + (c0 + cr) * 1024 + k0 + 4 * kq) = o;
  }
}

// ---------------------------------------------------------------------------
// kse: se[k] = ascending-c sequential fp32 chain of E[k][c]^2 (bit-faithful)
// ---------------------------------------------------------------------------
__global__ __launch_bounds__(256) void kse(float* __restrict__ out) {
  const int k = blockIdx.x * 256 + threadIdx.x;
  const float* Et = out + ET_OFF;
  float acc = 0.0f;
  #pragma unroll 8
  for (int c = 0; c < 256; c++) {
    float v = Et[c * 1024 + k];
    acc = __fadd_rn(acc, __fmul_rn(v, v));
  }
  out[k] = acc;
}

// ---------------------------------------------------------------------------
// ke1: e1 = bf16_rne(E), [1024][256] row-major (B-operand source)
// ---------------------------------------------------------------------------
__global__ __launch_bounds__(256) void ke1(const float* __restrict__ E,
                                           float* __restrict__ out) {
  unsigned short* e1 = (unsigned short*)(out + E1_OFF);
  int g = blockIdx.x * 256 + threadIdx.x;      // 65536 threads x 4 elems
  float4 v = *(const float4*)(E + 4 * g);
  ushort4 o;
  o.x = bf16rne(v.x); o.y = bf16rne(v.y); o.z = bf16rne(v.z); o.w = bf16rne(v.w);
  *(ushort4*)(e1 + 4 * g) = o;
}

// ---------------------------------------------------------------------------
// kzt: zt[b][n][c] = bf16_rne(zz[c][n]).  zz[c][n] = z.flat[b*262144 +
// m*1024 + 4c + w0] with n = w0*256 + m.  Row n holds 256 contiguous bf16
// channels -> A-frag loads are per-lane 16B contiguous.
// ---------------------------------------------------------------------------
__global__ __launch_bounds__(256) void kzt(const float* __restrict__ z,
                                           float* __restrict__ out) {
  __shared__ float tile[16][1028];   // 16 z-rows x 1024, pad 1028
  unsigned short* zt = (unsigned short*)(out + ZT_OFF);
  const int mg = blockIdx.x;         // 0..15 (16-row group)
  const int b  = blockIdx.y;         // 0..31
  const int t = threadIdx.x;
  #pragma unroll
  for (int i = 0; i < 16; i++) {     // row m=i, q=t: coalesced float4 loads
    float4 v = *(const float4*)(z + (size_t)b * 262144 + (size_t)(mg * 16 + i) * 1024 + 4 * t);
    *(float4*)&tile[i][4 * t] = v;
  }
  __syncthreads();
  const int m = t & 15, w0 = (t >> 4) & 3;   // R = t&63 spans (m,w0)
  const int n = w0 * 256 + mg * 16 + m;
  #pragma unroll
  for (int i = 0; i < 8; i++) {
    int g = 4 * i + (t >> 6);        // 0..31: 8-channel group
    int c0 = 8 * g;
    unsigned short o[8];
    #pragma unroll
    for (int j = 0; j < 8; j++)
      o[j] = bf16rne(tile[m][4 * (c0 + j) + w0]);
    *(uint4*)(zt + ((size_t)(b * 1024 + n)) * 256 + c0) = *(const uint4*)o;
  }
}

// ---------------------------------------------------------------------------
// kmain: MFMA approximate distances + provably-sound exact rescreen.
// R3 change: R2 spilled ~100 VGPRs to scratch (A_[4][8]=128 VGPR + acc +
// scalars > 220 live; reported VGPR_Count=128; MfmaUtil 2.5% = pure scratch
// stall, ~1 GB scratch traffic).  Fix: T (px w0-group) becomes an OUTER
// 4-pass loop.  Per pass: A = 8 v8s = 32 VGPR, B streams 32, acc 4,
// scalars ~12 -> ~100 live, no spill.  B (e1, 512 KB, L2-resident) is
// re-read 4x — ~30 us aggregate L2 traffic, hidden by 2 waves/SIMD.
// Candidate machinery is per-p and p == T (mod 4) partitions across passes,
// so peel/retro-append logic is per-pass verbatim.  Numerics unchanged.
// ---------------------------------------------------------------------------
__global__ __launch_bounds__(256, 2) void kmain(const float* __restrict__ z,
                                                const float* __restrict__ E,
                                                float* __restrict__ out) {
  __shared__ __attribute__((aligned(16))) float VsT[256][65];  // exact z, [c][p]
  __shared__ __attribute__((aligned(16))) float szs[64];
  __shared__ __attribute__((aligned(16))) float dmins[64];
  __shared__ int   candK[64 * CAP];
  __shared__ float candD[64 * CAP];
  __shared__ int   cnt[64];

  const int t = threadIdx.x;
  const int ccg = blockIdx.x, b = blockIdx.y;
  const int cc0 = ccg * 16;
  const int lane = t & 63, w = t >> 6;
  const int r = t & 15, h = (t >> 4) & 3;
  const float* zb = z + (size_t)b * 262144;
  const float* se_g = out;
  const unsigned short* e1 = (const unsigned short*)(out + E1_OFF);
  const unsigned short* zt = (const unsigned short*)(out + ZT_OFF);

  if (t < 64) { cnt[t] = 0; dmins[t] = 3.4e38f; }

  // ---- stage VsT[c][p] = z[row cc0+i][4c+w0], p = 4i+w0 ----
  #pragma unroll
  for (int i = 0; i < 16; i++) {
    float4 v = *(const float4*)(zb + (cc0 + i) * 1024 + 4 * t);
    *(float4*)&VsT[t][4 * i] = v;
  }
  __syncthreads();

  // ---- sz: exact ascending-c chain per px (wave 0) ----
  if (t < 64) {
    float a = 0.0f;
    #pragma unroll 8
    for (int c = 0; c < 256; c++)
      a = __fadd_rn(a, __fmul_rn(VsT[c][t], VsT[c][t]));
    szs[t] = a;
  }
  __syncthreads();

  volatile float* dminv = dmins;   // stale reads sound: threshold >= final min

  #pragma unroll 1
  for (int T = 0; T < 4; T++) {
    // A-frags for this px-group: 8 contiguous 16B loads from zt
    v8s A_[8];
    const unsigned short* abase =
        zt + ((size_t)(b * 1024 + T * 256 + cc0 + r)) * 256 + 8 * h;
    #pragma unroll
    for (int s = 0; s < 8; s++)
      A_[s] = *(const v8s*)(abase + 32 * s);

    float szr4[4];
    #pragma unroll
    for (int reg = 0; reg < 4; reg++) szr4[reg] = szs[16 * h + 4 * reg + T];

    float bestd4[4], d04[4];
    #pragma unroll
    for (int reg = 0; reg < 4; reg++) { bestd4[reg] = 3.4e38f; d04[reg] = 3.4e38f; }

    for (int ti = 0; ti < 16; ti++) {
      const int code0 = ti * 64 + w * 16;
      const unsigned short* bb = e1 + (size_t)(code0 + r) * 256 + 8 * h;
      v4f acc = (v4f){0.f, 0.f, 0.f, 0.f};
      #pragma unroll
      for (int s = 0; s < 8; s++) {
        v8s B_ = *(const v8s*)(bb + 32 * s);
        acc = __builtin_amdgcn_mfma_f32_16x16x32_bf16(A_[s], B_, acc, 0, 0, 0);
      }
      const int kl = code0 + r;          // this lane's D-column code
      const float se_l = se_g[kl];
      #pragma unroll
      for (int reg = 0; reg < 4; reg++) {
        const int p = 16 * h + 4 * reg + T;   // px = (4h+reg)*4 + T
        float dd = (se_l + szr4[reg]) - 2.0f * acc[reg];
        float thr = fminf(bestd4[reg], dminv[p]);
        if (ti == 0) {
          d04[reg] = dd;               // peel: no threshold yet; retro-append
        } else if (dd <= thr + WWIN) {
          int o = atomicAdd(&cnt[p], 1);
          if (o < CAP) { candK[p * CAP + o] = kl; candD[p * CAP + o] = dd; }
        }
        if (dd < bestd4[reg]) {
          bestd4[reg] = dd;
          atomicMin((int*)&dmins[p], __float_as_int(dd));  // positive: int-order ok
        }
      }
    }

    // ---- retro-append this pass's tile 0 against (near-)final min ----
    #pragma unroll
    for (int reg = 0; reg < 4; reg++) {
      const int p = 16 * h + 4 * reg + T;
      float dd = d04[reg];
      if (dd <= dminv[p] + WWIN) {
        int o = atomicAdd(&cnt[p], 1);
        if (o < CAP) { candK[p * CAP + o] = w * 16 + r; candD[p * CAP + o] = dd; }
      }
    }
  }
  __syncthreads();   // all appends + final dmins visible

  // ---- exact rescreen: bit-identical fp32 chain for surviving candidates ----
  for (int i = t; i < 64 * CAP; i += 256) {
    int p = i / CAP, slot = i - p * CAP;
    int cn = cnt[p];
    if (cn > CAP || slot >= cn) continue;     // overflow px -> fallback
    float dd = candD[i];
    if (dd > dmins[p] + WWIN) { candD[i] = 3.4e38f; continue; }
    int k = candK[i];
    const float* er = E + (size_t)k * 256;
    float dot = 0.0f;
    #pragma unroll 8
    for (int c = 0; c < 256; c++)
      dot = __fmaf_rn(VsT[c][p], er[c], dot);
    candD[i] = __fsub_rn(__fadd_rn(se_g[k], szs[p]), __fmul_rn(2.0f, dot));
  }
  __syncthreads();

  // ---- winners: lexicographic (d,k) min == first-index argmin ----
  if (t < 64) {
    int p = t, cn = cnt[p];
    if (cn <= CAP) {
      float bd = 3.4e38f; int bi = 0x7FFFFFFF;
      for (int s2 = 0; s2 < cn; s2++) {
        float d2 = candD[p * CAP + s2]; int k2 = candK[p * CAP + s2];
        if (d2 < bd || (d2 == bd && k2 < bi)) { bd = d2; bi = k2; }
      }
      int rr = p >> 2, w0 = p & 3;
      out[IDX_OFF + b * 1024 + (w0 * 256 + cc0 + rr)] = (float)bi;
    }
  }

  // ---- fallback: overflowed px -> exact full scan by one wave (rare) ----
  for (int p = 0; p < 64; p++) {
    if (cnt[p] > CAP && (p & 3) == w) {
      float bd = 3.4e38f; int bi = 0x7FFFFFFF;
      for (int k = lane; k < 1024; k += 64) {
        const float* er = E + (size_t)k * 256;
        float dot = 0.0f;
        #pragma unroll 8
        for (int c = 0; c < 256; c++)
          dot = __fmaf_rn(VsT[c][p], er[c], dot);
        float d2 = __fsub_rn(__fadd_rn(se_g[k], szs[p]), __fmul_rn(2.0f, dot));
        if (d2 < bd || (d2 == bd && k < bi)) { bd = d2; bi = k; }
      }
      #pragma unroll
      for (int mm = 32; mm >= 1; mm >>= 1) {
        float d2 = __shfl_xor(bd, mm, 64);
        int i2 = __shfl_xor(bi, mm, 64);
        if (d2 < bd || (d2 == bd && i2 < bi)) { bd = d2; bi = i2; }
      }
      if (lane == 0) {
        int rr = p >> 2, w0 = p & 3;
        out[IDX_OFF + b * 1024 + (w0 * 256 + cc0 + rr)] = (float)bi;
      }
    }
  }
}

// ---------------------------------------------------------------------------
// kout: z_q_st = fl(zp + fl(zq - zp)); per-block loss partial -> d_ws
// ---------------------------------------------------------------------------
__global__ __launch_bounds__(256) void kout(const float* __restrict__ z,
                                            const float* __restrict__ E,
                                            float* __restrict__ out,
                                            float* __restrict__ ws) {
  __shared__ float red[4];
  const int t = threadIdx.x;
  const size_t g4 = (size_t)blockIdx.x * 256 + t;
  const size_t g = g4 * 4;
  const int b = (int)(g >> 18);
  const int c = (int)((g >> 10) & 255);
  const int n = (int)(g & 1023);

  float4 zp = *(const float4*)(z + g);
  float4 idxf = *(const float4*)(out + IDX_OFF + b * 1024 + n);
  int i0 = (int)idxf.x, i1 = (int)idxf.y, i2 = (int)idxf.z, i3 = (int)idxf.w;
  float q0 = E[i0 * 256 + c];
  float q1 = E[i1 * 256 + c];
  float q2 = E[i2 * 256 + c];
  float q3 = E[i3 * 256 + c];
  float d0 = __fsub_rn(q0, zp.x);
  float d1 = __fsub_rn(q1, zp.y);
  float d2 = __fsub_rn(q2, zp.z);
  float d3 = __fsub_rn(q3, zp.w);
  float4 o;
  o.x = __fadd_rn(zp.x, d0);
  o.y = __fadd_rn(zp.y, d1);
  o.z = __fadd_rn(zp.z, d2);
  o.w = __fadd_rn(zp.w, d3);
  *(float4*)(out + g) = o;

  float s = d0 * d0 + d1 * d1 + d2 * d2 + d3 * d3;
  #pragma unroll
  for (int off = 32; off > 0; off >>= 1) s += __shfl_down(s, off);
  if ((t & 63) == 0) red[t >> 6] = s;
  __syncthreads();
  if (t == 0) ws[blockIdx.x] = red[0] + red[1] + red[2] + red[3];
}

// ---------------------------------------------------------------------------
// kfin: loss = 1.25 * (sum(ws)/N)
// ---------------------------------------------------------------------------
__global__ __launch_bounds__(256) void kfin(const float* __restrict__ ws,
                                            float* __restrict__ out) {
  __shared__ float red[4];
  const int t = threadIdx.x;
  float s = 0.0f;
  #pragma unroll
  for (int i = 0; i < 32; i++) s += ws[t + 256 * i];
  #pragma unroll
  for (int off = 32; off > 0; off >>= 1) s += __shfl_down(s, off);
  if ((t & 63) == 0) red[t >> 6] = s;
  __syncthreads();
  if (t == 0) {
    float S = red[0] + red[1] + red[2] + red[3];
    float m = S / 8388608.0f;
    out[LOSS_OFF] = __fadd_rn(m, __fmul_rn(0.25f, m));
  }
}

extern "C" void kernel_launch(void* const* d_in, const int* in_sizes, int n_in,
                              void* d_out, int out_size, void* d_ws, size_t ws_size,
                              hipStream_t stream) {
  const float* z = (const float*)d_in[0];    // [32,256,32,32]
  const float* E = (const float*)d_in[1];    // [1024,256]
  float* out = (float*)d_out;
  float* ws = (float*)d_ws;

  ktr<<<dim3(16, 4), 256, 0, stream>>>(E, out);
  kse<<<dim3(4), 256, 0, stream>>>(out);
  ke1<<<dim3(256), 256, 0, stream>>>(E, out);
  kzt<<<dim3(16, 32), 256, 0, stream>>>(z, out);
  kmain<<<dim3(16, 32), 256, 0, stream>>>(z, E, out);
  kout<<<dim3(8192), 256, 0, stream>>>(z, E, out, ws);
  kfin<<<dim3(1), 256, 0, stream>>>(ws, out);
}

// Round 4
// 383.317 us; speedup vs baseline: 1.1341x; 1.1341x over previous
//
#include <hip/hip_runtime.h>
#include <stdint.h>

// Problem constants
#define ZSIZE   8388608      // 32*256*32*32
#define NPIX    32768        // 32*32*32
#define IDX_OFF ZSIZE        // idx output offset (floats) in d_out
#define LOSS_OFF (ZSIZE + NPIX)
#define ET_OFF  1024         // Et fp32 [256][1024] scratch (for kse)
#define E1_OFF  263168       // e1s swizzled bf16 (131072 floats = 512 KB)
#define ZT_OFF  394240       // zt bf16 [32][1024][256] (4194304 floats)
#define CAP     24           // candidate slots per pixel
#define WWIN    6.0e-3f      // window >= 2*eps_bound (eps<=2.3e-3 rigorous)

using v8s = __attribute__((ext_vector_type(8))) short;   // 8 bf16 (4 VGPR)
using v4f = __attribute__((ext_vector_type(4))) float;   // MFMA acc

__device__ __forceinline__ unsigned short bf16rne(float f) {
  unsigned u = __float_as_uint(f);
  return (unsigned short)((u + 0x7FFFu + ((u >> 16) & 1u)) >> 16);
}

// ---------------------------------------------------------------------------
// ktr: transpose embedding E[1024][256] -> Et[256][1024] (feeds kse only)
// ---------------------------------------------------------------------------
__global__ __launch_bounds__(256) void ktr(const float* __restrict__ E,
                                           float* __restrict__ out) {
  __shared__ float tile[64][65];
  const int k0 = blockIdx.x * 64;
  const int c0 = blockIdx.y * 64;
  const int t = threadIdx.x;
  #pragma unroll
  for (int i = 0; i < 4; i++) {
    int f = t + 256 * i;
    int r = f >> 4, q = f & 15;
    float4 e = *(const float4*)(E + (k0 + r) * 256 + c0 + 4 * q);
    tile[r][4 * q + 0] = e.x; tile[r][4 * q + 1] = e.y;
    tile[r][4 * q + 2] = e.z; tile[r][4 * q + 3] = e.w;
  }
  __syncthreads();
  #pragma unroll
  for (int i = 0; i < 4; i++) {
    int f = t + 256 * i;
    int cr = f >> 4, kq = f & 15;
    float4 o;
    o.x = tile[4 * kq + 0][cr];
    o.y = tile[4 * kq + 1][cr];
    o.z = tile[4 * kq + 2][cr];
    o.w = tile[4 * kq + 3][cr];
    *(float4*)(out + ET_OFF + (c0 + cr) * 1024 + k0 + 4 * kq) = o;
  }
}

// ---------------------------------------------------------------------------
// kse: se[k] = ascending-c sequential fp32 chain of E[k][c]^2 (bit-faithful)
// ---------------------------------------------------------------------------
__global__ __launch_bounds__(256) void kse(float* __restrict__ out) {
  const int k = blockIdx.x * 256 + threadIdx.x;
  const float* Et = out + ET_OFF;
  float acc = 0.0f;
  #pragma unroll 8
  for (int c = 0; c < 256; c++) {
    float v = Et[c * 1024 + k];
    acc = __fadd_rn(acc, __fmul_rn(v, v));
  }
  out[k] = acc;
}

// ---------------------------------------------------------------------------
// kes: swizzled bf16 embedding in MFMA B-fragment order.
// e1s[tile][s][lane] (16B chunks): tile = code0/16 (0..63), s = 0..7,
// lane = 0..63 (r=lane&15, h=(lane>>4)&3).
// chunk = bf16(E[16*tile + r][8*h + 32*s + 0..7]).
// In kmain a wave's B-load for (tile,s) is then 64 lanes x 16B = 1KB
// CONTIGUOUS (vs R3's 16-line gather: 16x fewer L1 lines on the dominant
// ~1GB L2-read stream).
// ---------------------------------------------------------------------------
__global__ __launch_bounds__(256) void kes(const float* __restrict__ E,
                                           float* __restrict__ out) {
  unsigned short* e1s = (unsigned short*)(out + E1_OFF);
  const int tile = blockIdx.x;       // 0..63
  const int t = threadIdx.x;
  #pragma unroll
  for (int i = 0; i < 2; i++) {
    int chunk = t + 256 * i;         // 0..511
    int s = chunk >> 6, lane = chunk & 63;
    int r = lane & 15, h = (lane >> 4) & 3;
    const float* src = E + (16 * tile + r) * 256 + 8 * h + 32 * s;
    unsigned short o[8];
    #pragma unroll
    for (int j = 0; j < 8; j++) o[j] = bf16rne(src[j]);
    *(uint4*)(e1s + (size_t)tile * 4096 + (size_t)chunk * 8) = *(const uint4*)o;
  }
}

// ---------------------------------------------------------------------------
// kzt: zt[b][n][c] = bf16_rne(zz[c][n]).  zz[c][n] = z.flat[b*262144 +
// m*1024 + 4c + w0] with n = w0*256 + m.  Row n holds 256 contiguous bf16
// channels -> A-frag loads are per-lane 16B contiguous.
// ---------------------------------------------------------------------------
__global__ __launch_bounds__(256) void kzt(const float* __restrict__ z,
                                           float* __restrict__ out) {
  __shared__ float tile[16][1028];   // 16 z-rows x 1024, pad 1028
  unsigned short* zt = (unsigned short*)(out + ZT_OFF);
  const int mg = blockIdx.x;         // 0..15 (16-row group)
  const int b  = blockIdx.y;         // 0..31
  const int t = threadIdx.x;
  #pragma unroll
  for (int i = 0; i < 16; i++) {     // row m=i, q=t: coalesced float4 loads
    float4 v = *(const float4*)(z + (size_t)b * 262144 + (size_t)(mg * 16 + i) * 1024 + 4 * t);
    *(float4*)&tile[i][4 * t] = v;
  }
  __syncthreads();
  const int m = t & 15, w0 = (t >> 4) & 3;   // R = t&63 spans (m,w0)
  const int n = w0 * 256 + mg * 16 + m;
  #pragma unroll
  for (int i = 0; i < 8; i++) {
    int g = 4 * i + (t >> 6);        // 0..31: 8-channel group
    int c0 = 8 * g;
    unsigned short o[8];
    #pragma unroll
    for (int j = 0; j < 8; j++)
      o[j] = bf16rne(tile[m][4 * (c0 + j) + w0]);
    *(uint4*)(zt + ((size_t)(b * 1024 + n)) * 256 + c0) = *(const uint4*)o;
  }
}

// ---------------------------------------------------------------------------
// kmain: MFMA approximate distances + provably-sound exact rescreen.
// R4 change: R3's 325us with ALL pipes idle (Mfma 2%, VALU 6%) was the
// candidate machinery: mid-flight thresholds (own-lane history + laggy
// shared dminv under wave skew) ballooned appends past CAP -> the exact
// fallback full-scan (50-100k cy/px) ran for a large pixel fraction.
// Fix = two-phase per T-pass:
//   1) min phase: clean unrolled ti-loop (B-load+MFMA+dd->ddv[64] regs,
//      local bestd only; NO atomics/volatile/branches -> pipelineable),
//   2) atomicMin + barrier -> dmins[p] EXACT final approx-min,
//   3) append phase: replay ddv vs dmin+W.  lambda ~ 7/px, P(>CAP) ~ 1e-8
//      -> fallback is dead code.  Soundness: winner k* has
//      dd(k*) <= d(k*)+eps <= d(k)+eps <= dd(k)+2eps  => dd(k*) <= dmin+2eps,
//      W=6e-3 >= 2*eps (eps<=2.3e-3).  Exact rescreen unchanged (bit-exact
//      ascending-c fp32 chain; absmax=0 in R2/R3 confirms).
// B now loads from kes's swizzled layout: 1KB contiguous per wave-load.
// ---------------------------------------------------------------------------
__global__ __launch_bounds__(256, 2) void kmain(const float* __restrict__ z,
                                                const float* __restrict__ E,
                                                float* __restrict__ out) {
  __shared__ __attribute__((aligned(16))) float VsT[256][65];  // exact z, [c][p]
  __shared__ __attribute__((aligned(16))) float szs[64];
  __shared__ __attribute__((aligned(16))) float dmins[64];
  __shared__ int   candK[64 * CAP];
  __shared__ float candD[64 * CAP];
  __shared__ int   cnt[64];

  const int t = threadIdx.x;
  const int ccg = blockIdx.x, b = blockIdx.y;
  const int cc0 = ccg * 16;
  const int lane = t & 63, w = t >> 6;
  const int r = t & 15, h = (t >> 4) & 3;
  const float* zb = z + (size_t)b * 262144;
  const float* se_g = out;
  const unsigned short* e1s = (const unsigned short*)(out + E1_OFF);
  const unsigned short* zt = (const unsigned short*)(out + ZT_OFF);

  if (t < 64) { cnt[t] = 0; dmins[t] = 3.4e38f; }

  // ---- stage VsT[c][p] = z[row cc0+i][4c+w0], p = 4i+w0 ----
  #pragma unroll
  for (int i = 0; i < 16; i++) {
    float4 v = *(const float4*)(zb + (cc0 + i) * 1024 + 4 * t);
    *(float4*)&VsT[t][4 * i] = v;
  }
  __syncthreads();

  // ---- sz: exact ascending-c chain; 16 px per wave (lanes 0-15) ----
  if (lane < 16) {
    const int p = w * 16 + lane;
    float a = 0.0f;
    #pragma unroll 8
    for (int c = 0; c < 256; c++)
      a = __fadd_rn(a, __fmul_rn(VsT[c][p], VsT[c][p]));
    szs[p] = a;
  }
  __syncthreads();

  // ---- per-lane se for its 16 codes (independent of T) ----
  float se16r[16];
  #pragma unroll
  for (int ti = 0; ti < 16; ti++) se16r[ti] = se_g[ti * 64 + w * 16 + r];

  #pragma unroll 1
  for (int T = 0; T < 4; T++) {
    // A-frags for this px-group: 8 contiguous 16B loads from zt
    v8s A_[8];
    const unsigned short* abase =
        zt + ((size_t)(b * 1024 + T * 256 + cc0 + r)) * 256 + 8 * h;
    #pragma unroll
    for (int s = 0; s < 8; s++)
      A_[s] = *(const v8s*)(abase + 32 * s);

    float szr4[4];
    #pragma unroll
    for (int reg = 0; reg < 4; reg++) szr4[reg] = szs[16 * h + 4 * reg + T];

    // ---- phase 1: min scan, dd values kept in registers ----
    float ddv[64];                    // statically indexed (full unroll)
    float bestd4[4];
    #pragma unroll
    for (int reg = 0; reg < 4; reg++) bestd4[reg] = 3.4e38f;

    #pragma unroll
    for (int ti = 0; ti < 16; ti++) {
      const unsigned short* bb = e1s + (size_t)(4 * ti + w) * 4096 + lane * 8;
      v4f acc = (v4f){0.f, 0.f, 0.f, 0.f};
      #pragma unroll
      for (int s = 0; s < 8; s++) {
        v8s B_ = *(const v8s*)(bb + 512 * s);
        acc = __builtin_amdgcn_mfma_f32_16x16x32_bf16(A_[s], B_, acc, 0, 0, 0);
      }
      #pragma unroll
      for (int reg = 0; reg < 4; reg++) {
        float dd = (se16r[ti] + szr4[reg]) - 2.0f * acc[reg];
        ddv[4 * ti + reg] = dd;
        bestd4[reg] = fminf(bestd4[reg], dd);
      }
    }

    #pragma unroll
    for (int reg = 0; reg < 4; reg++)
      atomicMin((int*)&dmins[16 * h + 4 * reg + T],
                __float_as_int(bestd4[reg]));   // positive floats: int-order ok
    __syncthreads();                  // dmins final for this pass's pixels

    // ---- phase 2: append with exact final threshold ----
    float thr4[4];
    #pragma unroll
    for (int reg = 0; reg < 4; reg++)
      thr4[reg] = dmins[16 * h + 4 * reg + T] + WWIN;
    #pragma unroll
    for (int ti = 0; ti < 16; ti++) {
      #pragma unroll
      for (int reg = 0; reg < 4; reg++) {
        float dd = ddv[4 * ti + reg];
        if (dd <= thr4[reg]) {
          int p = 16 * h + 4 * reg + T;
          int o = atomicAdd(&cnt[p], 1);
          if (o < CAP) {
            candK[p * CAP + o] = ti * 64 + w * 16 + r;
            candD[p * CAP + o] = dd;
          }
        }
      }
    }
  }
  __syncthreads();   // all appends visible

  // ---- exact rescreen: bit-identical fp32 chain for surviving candidates ----
  for (int i = t; i < 64 * CAP; i += 256) {
    int p = i / CAP, slot = i - p * CAP;
    int cn = cnt[p];
    if (cn > CAP || slot >= cn) continue;     // overflow px -> fallback
    int k = candK[i];
    const float* er = E + (size_t)k * 256;
    float dot = 0.0f;
    #pragma unroll 8
    for (int c = 0; c < 256; c++)
      dot = __fmaf_rn(VsT[c][p], er[c], dot);
    candD[i] = __fsub_rn(__fadd_rn(se_g[k], szs[p]), __fmul_rn(2.0f, dot));
  }
  __syncthreads();

  // ---- winners: lexicographic (d,k) min == first-index argmin ----
  if (t < 64) {
    int p = t, cn = cnt[p];
    if (cn <= CAP) {
      float bd = 3.4e38f; int bi = 0x7FFFFFFF;
      for (int s2 = 0; s2 < cn; s2++) {
        float d2 = candD[p * CAP + s2]; int k2 = candK[p * CAP + s2];
        if (d2 < bd || (d2 == bd && k2 < bi)) { bd = d2; bi = k2; }
      }
      int rr = p >> 2, w0 = p & 3;
      out[IDX_OFF + b * 1024 + (w0 * 256 + cc0 + rr)] = (float)bi;
    }
  }

  // ---- fallback: overflowed px -> exact full scan by one wave (dead code
  // in practice: P(cnt>CAP) ~ 1e-8/px with exact-final threshold) ----
  for (int p = 0; p < 64; p++) {
    if (cnt[p] > CAP && (p & 3) == w) {
      float bd = 3.4e38f; int bi = 0x7FFFFFFF;
      for (int k = lane; k < 1024; k += 64) {
        const float* er = E + (size_t)k * 256;
        float dot = 0.0f;
        #pragma unroll 8
        for (int c = 0; c < 256; c++)
          dot = __fmaf_rn(VsT[c][p], er[c], dot);
        float d2 = __fsub_rn(__fadd_rn(se_g[k], szs[p]), __fmul_rn(2.0f, dot));
        if (d2 < bd || (d2 == bd && k < bi)) { bd = d2; bi = k; }
      }
      #pragma unroll
      for (int mm = 32; mm >= 1; mm >>= 1) {
        float d2 = __shfl_xor(bd, mm, 64);
        int i2 = __shfl_xor(bi, mm, 64);
        if (d2 < bd || (d2 == bd && i2 < bi)) { bd = d2; bi = i2; }
      }
      if (lane == 0) {
        int rr = p >> 2, w0 = p & 3;
        out[IDX_OFF + b * 1024 + (w0 * 256 + cc0 + rr)] = (float)bi;
      }
    }
  }
}

// ---------------------------------------------------------------------------
// kout: z_q_st = fl(zp + fl(zq - zp)); per-block loss partial -> d_ws
// ---------------------------------------------------------------------------
__global__ __launch_bounds__(256) void kout(const float* __restrict__ z,
                                            const float* __restrict__ E,
                                            float* __restrict__ out,
                                            float* __restrict__ ws) {
  __shared__ float red[4];
  const int t = threadIdx.x;
  const size_t g4 = (size_t)blockIdx.x * 256 + t;
  const size_t g = g4 * 4;
  const int b = (int)(g >> 18);
  const int c = (int)((g >> 10) & 255);
  const int n = (int)(g & 1023);

  float4 zp = *(const float4*)(z + g);
  float4 idxf = *(const float4*)(out + IDX_OFF + b * 1024 + n);
  int i0 = (int)idxf.x, i1 = (int)idxf.y, i2 = (int)idxf.z, i3 = (int)idxf.w;
  float q0 = E[i0 * 256 + c];
  float q1 = E[i1 * 256 + c];
  float q2 = E[i2 * 256 + c];
  float q3 = E[i3 * 256 + c];
  float d0 = __fsub_rn(q0, zp.x);
  float d1 = __fsub_rn(q1, zp.y);
  float d2 = __fsub_rn(q2, zp.z);
  float d3 = __fsub_rn(q3, zp.w);
  float4 o;
  o.x = __fadd_rn(zp.x, d0);
  o.y = __fadd_rn(zp.y, d1);
  o.z = __fadd_rn(zp.z, d2);
  o.w = __fadd_rn(zp.w, d3);
  *(float4*)(out + g) = o;

  float s = d0 * d0 + d1 * d1 + d2 * d2 + d3 * d3;
  #pragma unroll
  for (int off = 32; off > 0; off >>= 1) s += __shfl_down(s, off);
  if ((t & 63) == 0) red[t >> 6] = s;
  __syncthreads();
  if (t == 0) ws[blockIdx.x] = red[0] + red[1] + red[2] + red[3];
}

// ---------------------------------------------------------------------------
// kfin: loss = 1.25 * (sum(ws)/N)
// ---------------------------------------------------------------------------
__global__ __launch_bounds__(256) void kfin(const float* __restrict__ ws,
                                            float* __restrict__ out) {
  __shared__ float red[4];
  const int t = threadIdx.x;
  float s = 0.0f;
  #pragma unroll
  for (int i = 0; i < 32; i++) s += ws[t + 256 * i];
  #pragma unroll
  for (int off = 32; off > 0; off >>= 1) s += __shfl_down(s, off);
  if ((t & 63) == 0) red[t >> 6] = s;
  __syncthreads();
  if (t == 0) {
    float S = red[0] + red[1] + red[2] + red[3];
    float m = S / 8388608.0f;
    out[LOSS_OFF] = __fadd_rn(m, __fmul_rn(0.25f, m));
  }
}

extern "C" void kernel_launch(void* const* d_in, const int* in_sizes, int n_in,
                              void* d_out, int out_size, void* d_ws, size_t ws_size,
                              hipStream_t stream) {
  const float* z = (const float*)d_in[0];    // [32,256,32,32]
  const float* E = (const float*)d_in[1];    // [1024,256]
  float* out = (float*)d_out;
  float* ws = (float*)d_ws;

  ktr<<<dim3(16, 4), 256, 0, stream>>>(E, out);
  kse<<<dim3(4), 256, 0, stream>>>(out);
  kes<<<dim3(64), 256, 0, stream>>>(E, out);
  kzt<<<dim3(16, 32), 256, 0, stream>>>(z, out);
  kmain<<<dim3(16, 32), 256, 0, stream>>>(z, E, out);
  kout<<<dim3(8192), 256, 0, stream>>>(z, E, out, ws);
  kfin<<<dim3(1), 256, 0, stream>>>(ws, out);
}

// Round 5
// 249.834 us; speedup vs baseline: 1.7401x; 1.5343x over previous
//
#include <hip/hip_runtime.h>
#include <stdint.h>

// Problem constants
#define ZSIZE   8388608      // 32*256*32*32
#define NPIX    32768        // 32*32*32
#define IDX_OFF ZSIZE        // idx output offset (floats) in d_out
#define LOSS_OFF (ZSIZE + NPIX)
#define ET_OFF  1024         // Et fp32 [256][1024] scratch (for kse)
#define E1_OFF  263168       // e1s swizzled bf16 (131072 floats = 512 KB)
#define ZT_OFF  394240       // zt bf16 [32][1024][256] (4194304 floats)
#define CAP     24           // candidate slots per pixel
#define WWIN    6.0e-3f      // window >= 2*eps_bound (eps<=2.4e-3 rigorous)

using v8s = __attribute__((ext_vector_type(8))) short;   // 8 bf16 (4 VGPR)
using v4f = __attribute__((ext_vector_type(4))) float;   // MFMA acc

__device__ __forceinline__ unsigned short bf16rne(float f) {
  unsigned u = __float_as_uint(f);
  return (unsigned short)((u + 0x7FFFu + ((u >> 16) & 1u)) >> 16);
}

// ---------------------------------------------------------------------------
// ktr: transpose embedding E[1024][256] -> Et[256][1024] (feeds kse only)
// ---------------------------------------------------------------------------
__global__ __launch_bounds__(256) void ktr(const float* __restrict__ E,
                                           float* __restrict__ out) {
  __shared__ float tile[64][65];
  const int k0 = blockIdx.x * 64;
  const int c0 = blockIdx.y * 64;
  const int t = threadIdx.x;
  #pragma unroll
  for (int i = 0; i < 4; i++) {
    int f = t + 256 * i;
    int r = f >> 4, q = f & 15;
    float4 e = *(const float4*)(E + (k0 + r) * 256 + c0 + 4 * q);
    tile[r][4 * q + 0] = e.x; tile[r][4 * q + 1] = e.y;
    tile[r][4 * q + 2] = e.z; tile[r][4 * q + 3] = e.w;
  }
  __syncthreads();
  #pragma unroll
  for (int i = 0; i < 4; i++) {
    int f = t + 256 * i;
    int cr = f >> 4, kq = f & 15;
    float4 o;
    o.x = tile[4 * kq + 0][cr];
    o.y = tile[4 * kq + 1][cr];
    o.z = tile[4 * kq + 2][cr];
    o.w = tile[4 * kq + 3][cr];
    *(float4*)(out + ET_OFF + (c0 + cr) * 1024 + k0 + 4 * kq) = o;
  }
}

// ---------------------------------------------------------------------------
// kse: se[k] = ascending-c sequential fp32 chain of E[k][c]^2 (bit-faithful)
// ---------------------------------------------------------------------------
__global__ __launch_bounds__(256) void kse(float* __restrict__ out) {
  const int k = blockIdx.x * 256 + threadIdx.x;
  const float* Et = out + ET_OFF;
  float acc = 0.0f;
  #pragma unroll 8
  for (int c = 0; c < 256; c++) {
    float v = Et[c * 1024 + k];
    acc = __fadd_rn(acc, __fmul_rn(v, v));
  }
  out[k] = acc;
}

// ---------------------------------------------------------------------------
// kes: swizzled bf16 embedding in MFMA B-fragment order.
// e1s[tile][s][lane] (16B chunks): tile = code0/16 (0..63), s = 0..7,
// lane = 0..63 (r=lane&15, h=(lane>>4)&3).
// chunk = bf16(E[16*tile + r][8*h + 32*s + 0..7]).
// A wave's B-load for (tile,s) is 64 lanes x 16B = 1KB contiguous.
// ---------------------------------------------------------------------------
__global__ __launch_bounds__(256) void kes(const float* __restrict__ E,
                                           float* __restrict__ out) {
  unsigned short* e1s = (unsigned short*)(out + E1_OFF);
  const int tile = blockIdx.x;       // 0..63
  const int t = threadIdx.x;
  #pragma unroll
  for (int i = 0; i < 2; i++) {
    int chunk = t + 256 * i;         // 0..511
    int s = chunk >> 6, lane = chunk & 63;
    int r = lane & 15, h = (lane >> 4) & 3;
    const float* src = E + (16 * tile + r) * 256 + 8 * h + 32 * s;
    unsigned short o[8];
    #pragma unroll
    for (int j = 0; j < 8; j++) o[j] = bf16rne(src[j]);
    *(uint4*)(e1s + (size_t)tile * 4096 + (size_t)chunk * 8) = *(const uint4*)o;
  }
}

// ---------------------------------------------------------------------------
// kzt: zt[b][n][c] = bf16_rne(zz[c][n]).  n = w0*256 + m.  Row n holds 256
// contiguous bf16 channels -> A-frag loads are per-lane 16B contiguous.
// ---------------------------------------------------------------------------
__global__ __launch_bounds__(256) void kzt(const float* __restrict__ z,
                                           float* __restrict__ out) {
  __shared__ float tile[16][1028];   // 16 z-rows x 1024, pad 1028
  unsigned short* zt = (unsigned short*)(out + ZT_OFF);
  const int mg = blockIdx.x;         // 0..15 (16-row group)
  const int b  = blockIdx.y;         // 0..31
  const int t = threadIdx.x;
  #pragma unroll
  for (int i = 0; i < 16; i++) {     // row m=i, q=t: coalesced float4 loads
    float4 v = *(const float4*)(z + (size_t)b * 262144 + (size_t)(mg * 16 + i) * 1024 + 4 * t);
    *(float4*)&tile[i][4 * t] = v;
  }
  __syncthreads();
  const int m = t & 15, w0 = (t >> 4) & 3;   // R = t&63 spans (m,w0)
  const int n = w0 * 256 + mg * 16 + m;
  #pragma unroll
  for (int i = 0; i < 8; i++) {
    int g = 4 * i + (t >> 6);        // 0..31: 8-channel group
    int c0 = 8 * g;
    unsigned short o[8];
    #pragma unroll
    for (int j = 0; j < 8; j++)
      o[j] = bf16rne(tile[m][4 * (c0 + j) + w0]);
    *(uint4*)(zt + ((size_t)(b * 1024 + n)) * 256 + c0) = *(const uint4*)o;
  }
}

// ---------------------------------------------------------------------------
// kmain: MFMA approximate distances + provably-sound exact rescreen.
// R5 change: R4's ddv[64] cold register array (live across the phase
// barrier) was spilled -> 64 MB scratch writes + 130 MB reads = the 250us.
// Fix: phase 2 RECOMPUTES dd instead of storing it.  To keep e1s L2
// traffic flat (2 MB/block, same as R4) despite 2x MFMA passes, each pass
// processes a T-PAIR: two pixel groups share every streamed B fragment
// (A0/A1 = 64 hot VGPRs, reused 16x -> allocator keeps them).  No value
// lives across the barrier; peak live ~140 regs, all hot.
// dd is bit-identical between phases (x2.0 exact -> contraction-proof;
// MFMA deterministic) so the dd-min winner re-appends in phase 2; exact
// winner capture needs W >= 2*eps: eps <= 2^-8*||z||*||e||*2 <= 2.4e-3,
// W = 6e-3 ok.  Exact rescreen chain unchanged (absmax=0 in R2-R4).
// ---------------------------------------------------------------------------
__global__ __launch_bounds__(256, 2) void kmain(const float* __restrict__ z,
                                                const float* __restrict__ E,
                                                float* __restrict__ out) {
  __shared__ __attribute__((aligned(16))) float VsT[256][65];  // exact z, [c][p]
  __shared__ __attribute__((aligned(16))) float szs[64];
  __shared__ __attribute__((aligned(16))) float dmins[64];
  __shared__ int   candK[64 * CAP];
  __shared__ float candD[64 * CAP];
  __shared__ int   cnt[64];

  const int t = threadIdx.x;
  const int ccg = blockIdx.x, b = blockIdx.y;
  const int cc0 = ccg * 16;
  const int lane = t & 63, w = t >> 6;
  const int r = t & 15, h = (t >> 4) & 3;
  const float* zb = z + (size_t)b * 262144;
  const float* se_g = out;
  const unsigned short* e1s = (const unsigned short*)(out + E1_OFF);
  const unsigned short* zt = (const unsigned short*)(out + ZT_OFF);

  if (t < 64) { cnt[t] = 0; dmins[t] = 3.4e38f; }

  // ---- stage VsT[c][p] = z[row cc0+i][4c+w0], p = 4i+w0 ----
  #pragma unroll
  for (int i = 0; i < 16; i++) {
    float4 v = *(const float4*)(zb + (cc0 + i) * 1024 + 4 * t);
    *(float4*)&VsT[t][4 * i] = v;
  }
  __syncthreads();

  // ---- sz: exact ascending-c chain; 16 px per wave (lanes 0-15) ----
  if (lane < 16) {
    const int p = w * 16 + lane;
    float a = 0.0f;
    #pragma unroll 8
    for (int c = 0; c < 256; c++)
      a = __fadd_rn(a, __fmul_rn(VsT[c][p], VsT[c][p]));
    szs[p] = a;
  }
  __syncthreads();

  // ======== phase 1: min scan (nothing stored but 8 scalars) ========
  #pragma unroll 1
  for (int Tp = 0; Tp < 2; Tp++) {
    const int T0 = 2 * Tp, T1 = 2 * Tp + 1;
    v8s A0[8], A1[8];
    {
      const unsigned short* a0 =
          zt + ((size_t)(b * 1024 + T0 * 256 + cc0 + r)) * 256 + 8 * h;
      const unsigned short* a1 =
          zt + ((size_t)(b * 1024 + T1 * 256 + cc0 + r)) * 256 + 8 * h;
      #pragma unroll
      for (int s = 0; s < 8; s++) {
        A0[s] = *(const v8s*)(a0 + 32 * s);
        A1[s] = *(const v8s*)(a1 + 32 * s);
      }
    }
    float sz0[4], sz1[4], b0[4], b1[4];
    #pragma unroll
    for (int reg = 0; reg < 4; reg++) {
      sz0[reg] = szs[16 * h + 4 * reg + T0];
      sz1[reg] = szs[16 * h + 4 * reg + T1];
      b0[reg] = 3.4e38f; b1[reg] = 3.4e38f;
    }

    #pragma unroll 4
    for (int ti = 0; ti < 16; ti++) {
      const unsigned short* bb = e1s + (size_t)(4 * ti + w) * 4096 + lane * 8;
      v4f acc0 = (v4f){0.f, 0.f, 0.f, 0.f};
      v4f acc1 = (v4f){0.f, 0.f, 0.f, 0.f};
      #pragma unroll
      for (int s = 0; s < 8; s++) {
        v8s B_ = *(const v8s*)(bb + 512 * s);
        acc0 = __builtin_amdgcn_mfma_f32_16x16x32_bf16(A0[s], B_, acc0, 0, 0, 0);
        acc1 = __builtin_amdgcn_mfma_f32_16x16x32_bf16(A1[s], B_, acc1, 0, 0, 0);
      }
      float se_l = se_g[ti * 64 + w * 16 + r];
      #pragma unroll
      for (int reg = 0; reg < 4; reg++) {
        b0[reg] = fminf(b0[reg], (se_l + sz0[reg]) - 2.0f * acc0[reg]);
        b1[reg] = fminf(b1[reg], (se_l + sz1[reg]) - 2.0f * acc1[reg]);
      }
    }
    #pragma unroll
    for (int reg = 0; reg < 4; reg++) {
      atomicMin((int*)&dmins[16 * h + 4 * reg + T0], __float_as_int(b0[reg]));
      atomicMin((int*)&dmins[16 * h + 4 * reg + T1], __float_as_int(b1[reg]));
    }
  }
  __syncthreads();   // dmins exact-final

  // ======== phase 2: recompute dd, append dd <= dmin + W ========
  #pragma unroll 1
  for (int Tp = 0; Tp < 2; Tp++) {
    const int T0 = 2 * Tp, T1 = 2 * Tp + 1;
    v8s A0[8], A1[8];
    {
      const unsigned short* a0 =
          zt + ((size_t)(b * 1024 + T0 * 256 + cc0 + r)) * 256 + 8 * h;
      const unsigned short* a1 =
          zt + ((size_t)(b * 1024 + T1 * 256 + cc0 + r)) * 256 + 8 * h;
      #pragma unroll
      for (int s = 0; s < 8; s++) {
        A0[s] = *(const v8s*)(a0 + 32 * s);
        A1[s] = *(const v8s*)(a1 + 32 * s);
      }
    }
    float sz0[4], sz1[4], th0[4], th1[4];
    #pragma unroll
    for (int reg = 0; reg < 4; reg++) {
      sz0[reg] = szs[16 * h + 4 * reg + T0];
      sz1[reg] = szs[16 * h + 4 * reg + T1];
      th0[reg] = dmins[16 * h + 4 * reg + T0] + WWIN;
      th1[reg] = dmins[16 * h + 4 * reg + T1] + WWIN;
    }

    #pragma unroll 4
    for (int ti = 0; ti < 16; ti++) {
      const unsigned short* bb = e1s + (size_t)(4 * ti + w) * 4096 + lane * 8;
      v4f acc0 = (v4f){0.f, 0.f, 0.f, 0.f};
      v4f acc1 = (v4f){0.f, 0.f, 0.f, 0.f};
      #pragma unroll
      for (int s = 0; s < 8; s++) {
        v8s B_ = *(const v8s*)(bb + 512 * s);
        acc0 = __builtin_amdgcn_mfma_f32_16x16x32_bf16(A0[s], B_, acc0, 0, 0, 0);
        acc1 = __builtin_amdgcn_mfma_f32_16x16x32_bf16(A1[s], B_, acc1, 0, 0, 0);
      }
      float se_l = se_g[ti * 64 + w * 16 + r];
      const int kl = ti * 64 + w * 16 + r;
      #pragma unroll
      for (int reg = 0; reg < 4; reg++) {
        float dd0 = (se_l + sz0[reg]) - 2.0f * acc0[reg];
        if (dd0 <= th0[reg]) {
          int p = 16 * h + 4 * reg + T0;
          int o = atomicAdd(&cnt[p], 1);
          if (o < CAP) { candK[p * CAP + o] = kl; candD[p * CAP + o] = dd0; }
        }
        float dd1 = (se_l + sz1[reg]) - 2.0f * acc1[reg];
        if (dd1 <= th1[reg]) {
          int p = 16 * h + 4 * reg + T1;
          int o = atomicAdd(&cnt[p], 1);
          if (o < CAP) { candK[p * CAP + o] = kl; candD[p * CAP + o] = dd1; }
        }
      }
    }
  }
  __syncthreads();   // all appends visible

  // ---- exact rescreen: bit-identical fp32 chain for surviving candidates ----
  for (int i = t; i < 64 * CAP; i += 256) {
    int p = i / CAP, slot = i - p * CAP;
    int cn = cnt[p];
    if (cn > CAP || slot >= cn) continue;     // overflow px -> fallback
    int k = candK[i];
    const float* er = E + (size_t)k * 256;
    float dot = 0.0f;
    #pragma unroll 8
    for (int c = 0; c < 256; c++)
      dot = __fmaf_rn(VsT[c][p], er[c], dot);
    candD[i] = __fsub_rn(__fadd_rn(se_g[k], szs[p]), __fmul_rn(2.0f, dot));
  }
  __syncthreads();

  // ---- winners: lexicographic (d,k) min == first-index argmin ----
  if (t < 64) {
    int p = t, cn = cnt[p];
    if (cn <= CAP) {
      float bd = 3.4e38f; int bi = 0x7FFFFFFF;
      for (int s2 = 0; s2 < cn; s2++) {
        float d2 = candD[p * CAP + s2]; int k2 = candK[p * CAP + s2];
        if (d2 < bd || (d2 == bd && k2 < bi)) { bd = d2; bi = k2; }
      }
      int rr = p >> 2, w0 = p & 3;
      out[IDX_OFF + b * 1024 + (w0 * 256 + cc0 + rr)] = (float)bi;
    }
  }

  // ---- fallback: overflowed px -> exact full scan by one wave (dead code
  // in practice: exact-final threshold, lambda ~ 3/px, P(>24) ~ 1e-12) ----
  for (int p = 0; p < 64; p++) {
    if (cnt[p] > CAP && (p & 3) == w) {
      float bd = 3.4e38f; int bi = 0x7FFFFFFF;
      for (int k = lane; k < 1024; k += 64) {
        const float* er = E + (size_t)k * 256;
        float dot = 0.0f;
        #pragma unroll 8
        for (int c = 0; c < 256; c++)
          dot = __fmaf_rn(VsT[c][p], er[c], dot);
        float d2 = __fsub_rn(__fadd_rn(se_g[k], szs[p]), __fmul_rn(2.0f, dot));
        if (d2 < bd || (d2 == bd && k < bi)) { bd = d2; bi = k; }
      }
      #pragma unroll
      for (int mm = 32; mm >= 1; mm >>= 1) {
        float d2 = __shfl_xor(bd, mm, 64);
        int i2 = __shfl_xor(bi, mm, 64);
        if (d2 < bd || (d2 == bd && i2 < bi)) { bd = d2; bi = i2; }
      }
      if (lane == 0) {
        int rr = p >> 2, w0 = p & 3;
        out[IDX_OFF + b * 1024 + (w0 * 256 + cc0 + rr)] = (float)bi;
      }
    }
  }
}

// ---------------------------------------------------------------------------
// kout: z_q_st = fl(zp + fl(zq - zp)); per-block loss partial -> d_ws
// ---------------------------------------------------------------------------
__global__ __launch_bounds__(256) void kout(const float* __restrict__ z,
                                            const float* __restrict__ E,
                                            float* __restrict__ out,
                                            float* __restrict__ ws) {
  __shared__ float red[4];
  const int t = threadIdx.x;
  const size_t g4 = (size_t)blockIdx.x * 256 + t;
  const size_t g = g4 * 4;
  const int b = (int)(g >> 18);
  const int c = (int)((g >> 10) & 255);
  const int n = (int)(g & 1023);

  float4 zp = *(const float4*)(z + g);
  float4 idxf = *(const float4*)(out + IDX_OFF + b * 1024 + n);
  int i0 = (int)idxf.x, i1 = (int)idxf.y, i2 = (int)idxf.z, i3 = (int)idxf.w;
  float q0 = E[i0 * 256 + c];
  float q1 = E[i1 * 256 + c];
  float q2 = E[i2 * 256 + c];
  float q3 = E[i3 * 256 + c];
  float d0 = __fsub_rn(q0, zp.x);
  float d1 = __fsub_rn(q1, zp.y);
  float d2 = __fsub_rn(q2, zp.z);
  float d3 = __fsub_rn(q3, zp.w);
  float4 o;
  o.x = __fadd_rn(zp.x, d0);
  o.y = __fadd_rn(zp.y, d1);
  o.z = __fadd_rn(zp.z, d2);
  o.w = __fadd_rn(zp.w, d3);
  *(float4*)(out + g) = o;

  float s = d0 * d0 + d1 * d1 + d2 * d2 + d3 * d3;
  #pragma unroll
  for (int off = 32; off > 0; off >>= 1) s += __shfl_down(s, off);
  if ((t & 63) == 0) red[t >> 6] = s;
  __syncthreads();
  if (t == 0) ws[blockIdx.x] = red[0] + red[1] + red[2] + red[3];
}

// ---------------------------------------------------------------------------
// kfin: loss = 1.25 * (sum(ws)/N)
// ---------------------------------------------------------------------------
__global__ __launch_bounds__(256) void kfin(const float* __restrict__ ws,
                                            float* __restrict__ out) {
  __shared__ float red[4];
  const int t = threadIdx.x;
  float s = 0.0f;
  #pragma unroll
  for (int i = 0; i < 32; i++) s += ws[t + 256 * i];
  #pragma unroll
  for (int off = 32; off > 0; off >>= 1) s += __shfl_down(s, off);
  if ((t & 63) == 0) red[t >> 6] = s;
  __syncthreads();
  if (t == 0) {
    float S = red[0] + red[1] + red[2] + red[3];
    float m = S / 8388608.0f;
    out[LOSS_OFF] = __fadd_rn(m, __fmul_rn(0.25f, m));
  }
}

extern "C" void kernel_launch(void* const* d_in, const int* in_sizes, int n_in,
                              void* d_out, int out_size, void* d_ws, size_t ws_size,
                              hipStream_t stream) {
  const float* z = (const float*)d_in[0];    // [32,256,32,32]
  const float* E = (const float*)d_in[1];    // [1024,256]
  float* out = (float*)d_out;
  float* ws = (float*)d_ws;

  ktr<<<dim3(16, 4), 256, 0, stream>>>(E, out);
  kse<<<dim3(4), 256, 0, stream>>>(out);
  kes<<<dim3(64), 256, 0, stream>>>(E, out);
  kzt<<<dim3(16, 32), 256, 0, stream>>>(z, out);
  kmain<<<dim3(16, 32), 256, 0, stream>>>(z, E, out);
  kout<<<dim3(8192), 256, 0, stream>>>(z, E, out, ws);
  kfin<<<dim3(1), 256, 0, stream>>>(ws, out);
}